// Round 9
// baseline (478.166 us; speedup 1.0000x reference)
//
#include <hip/hip_runtime.h>

// Fused persistent stacked-GRU kernel for MI355X (gfx950).
// Round-9: THREE-stage pipeline, one barrier per phase, no intra-phase LDS
// round-trip anywhere. Phase f: p-waves compute p1/p2(t=f) + stage x; r-waves
// compute gate(t=f-1) AND main-GRU(t=f-2) -- all reads issued together, one
// lgkm wait. Handoffs cross exactly 1 barrier via parity dbuf:
//   AG[t&1]: h1h2+xg(t) written @f=t, read by gate @f=t+1
//   AR[t&1]: gate cols0-15 @f=t+1; xr(t) staged @f=t+1 (xrHold); read @f=t+2
//   AH[t&1]: h(t) written @f=t+2, read by main(t+1) @f=t+3
// 256 blocks x 8 rows, launch_bounds(512,2) (VGPR~105, no spill).

#define T_STEPS 512
#define B_BATCH 2048
#define D_IN    132
#define NROWS   8
#define NBLOCKS 256
#define STEP2   (B_BATCH * D_IN / 2)   // f32x2 per timestep
#define NITEMS  (NROWS * 66)           // 528 f32x2 per step per block

typedef _Float16 f16x8 __attribute__((ext_vector_type(8)));
typedef float    f32x4 __attribute__((ext_vector_type(4)));
typedef float    f32x2 __attribute__((ext_vector_type(2)));

#define MFMA16(a, b, c) __builtin_amdgcn_mfma_f32_16x16x32_f16((a), (b), (c), 0, 0, 0)

// LDS tiles [16][64] fp16 (1024 elems), all parity-double-buffered (+PX).
#define AP1   0      // x_p1 cols 0..48
#define AP2   2048   // x_p2 cols 0..48
#define AG    4096   // h1:0-19 h2:20-39 xg:40-47
#define AR    6144   // gate:0-15 xr:16-41
#define AP1H  8192   // h1 cols 0..19
#define AP2H  10240  // h2 cols 0..19
#define AH    12288  // h cols 0..63
#define LDS_N 14336
#define PX    1024

// Raw barrier: LDS visibility only (lgkmcnt), NO vmcnt drain -> HBM prefetch
// stays in flight across barriers. seq read-only, out write-only.
#define BARRIER() do { \
    asm volatile("s_waitcnt lgkmcnt(0)\n\ts_barrier" ::: "memory"); \
    __builtin_amdgcn_sched_barrier(0); \
  } while (0)

__device__ __forceinline__ int swz(int row, int col) {
  return row * 64 + (((col >> 3) ^ (row & 7)) << 3) + (col & 7);
}

__device__ __forceinline__ f16x8 ldsFrag(const _Float16* lds, int base, int lane, int kt) {
  int row = lane & 15;
  int blk = ((kt << 2) + (lane >> 4)) ^ (row & 7);
  return *reinterpret_cast<const f16x8*>(lds + base + row * 64 + blk * 8);
}

__device__ __forceinline__ f16x8 mkfrag(const float* W, int row, int K, int kbase, int lane, bool ok) {
  f16x8 f;
  int k0 = kbase + ((lane >> 4) << 3);
#pragma unroll
  for (int j = 0; j < 8; ++j) {
    int k = k0 + j;
    float v = 0.0f;
    if (ok && k < K) v = W[row * K + k];
    f[j] = (_Float16)v;
  }
  return f;
}

__device__ __forceinline__ float rcpf(float x) { return __builtin_amdgcn_rcpf(x); }
__device__ __forceinline__ float ex2(float x)  { return __builtin_amdgcn_exp2f(x); }

__global__ __launch_bounds__(512, 2) void rnn_fused(
    const float* __restrict__ seq,
    const float* __restrict__ p1Wih, const float* __restrict__ p1Whh,
    const float* __restrict__ p1bih, const float* __restrict__ p1bhh,
    const float* __restrict__ p2Wih, const float* __restrict__ p2Whh,
    const float* __restrict__ p2bih, const float* __restrict__ p2bhh,
    const float* __restrict__ gW,    const float* __restrict__ gb,
    const float* __restrict__ rWih,  const float* __restrict__ rWhh,
    const float* __restrict__ rbih,  const float* __restrict__ rbhh,
    float* __restrict__ out)
{
  __shared__ __align__(16) _Float16 lds[LDS_N];
  const int tid  = threadIdx.x;
  const int lane = tid & 63;
  const int wv   = tid >> 6;
  const bool isR = (wv < 4);
  const int b0   = blockIdx.x * NROWS;
  const int ul   = lane & 15;
  const int rowb = (lane >> 4) * 4;
  const float C1 = 1.44269504089f;

  for (int i = tid; i < LDS_N; i += 512) lds[i] = (_Float16)0.0f;

  // ---------------- r-wave state ----------------
  f16x8 fghr[2], fghz[2], fghn[2], fgir[2], fgiz[2], fgin[2], fgw[2];
  float nbr2 = 0, nbz2 = 0, bin2 = 0, bhn2 = 0, gbias = 0;
  float hq[4] = {0, 0, 0, 0};
  int uR = 0;
  int arw[4] = {0,0,0,0}, ahw[4] = {0,0,0,0};
  float* outp = nullptr;

  // ---------------- p-wave state ----------------
  f16x8 pgi0[2], pgi1[2], pgi2[2], pgh0, pgh1, pgh2;
  float nbr = 0, nbz = 0, bin = 0, bhn = 0;
  float h1q[4] = {0, 0, 0, 0};
  int apB = 0, aphB = 0, gcol = 0, up = 0; bool uok = false;
  // staging: 528 f32x2 items over 256 p-threads, 3 item-slots each
  int stAddr[3][2]; int ldIdx[3] = {0, 0, 0};
  bool stOK[3] = {false, false, false};
  bool clsXG[3] = {false, false, false}, clsXR[3] = {false, false, false};
  f32x2 xrHold[3];

  if (isR) {
    uR = wv * 16 + ul;
    fghr[0] = mkfrag(rWhh,       uR, 64,  0, lane, true);
    fghr[1] = mkfrag(rWhh,       uR, 64, 32, lane, true);
    fghz[0] = mkfrag(rWhh,  64 + uR, 64,  0, lane, true);
    fghz[1] = mkfrag(rWhh,  64 + uR, 64, 32, lane, true);
    fghn[0] = mkfrag(rWhh, 128 + uR, 64,  0, lane, true);
    fghn[1] = mkfrag(rWhh, 128 + uR, 64, 32, lane, true);
    fgir[0] = mkfrag(rWih,       uR, 42,  0, lane, true);
    fgir[1] = mkfrag(rWih,       uR, 42, 32, lane, true);
    fgiz[0] = mkfrag(rWih,  64 + uR, 42,  0, lane, true);
    fgiz[1] = mkfrag(rWih,  64 + uR, 42, 32, lane, true);
    fgin[0] = mkfrag(rWih, 128 + uR, 42,  0, lane, true);
    fgin[1] = mkfrag(rWih, 128 + uR, 42, 32, lane, true);
    fgw[0]  = mkfrag(gW, ul, 48,  0, lane, true);
    fgw[1]  = mkfrag(gW, ul, 48, 32, lane, true);
    nbr2 = -C1 * (rbih[uR] + rbhh[uR]);
    nbz2 = -C1 * (rbih[64 + uR] + rbhh[64 + uR]);
    bin2 = rbih[128 + uR]; bhn2 = rbhh[128 + uR];
    gbias = gb[ul];
#pragma unroll
    for (int q = 0; q < 4; ++q) {
      arw[q] = AR + swz(rowb + q, ul);
      ahw[q] = AH + swz(rowb + q, uR);
    }
    outp = out + (size_t)b0 * 64 + uR;
  } else {
    const int pw  = wv - 4;
    const int gru = pw >> 1;
    const int s   = pw & 1;
    const float* Wih = gru ? p2Wih : p1Wih;
    const float* Whh = gru ? p2Whh : p1Whh;
    const float* bih = gru ? p2bih : p1bih;
    const float* bhh = gru ? p2bhh : p1bhh;
    up  = s * 16 + ul;
    uok = (up < 20);
    pgi0[0] = mkfrag(Wih,      up, 49,  0, lane, uok);
    pgi0[1] = mkfrag(Wih,      up, 49, 32, lane, uok);
    pgh0    = mkfrag(Whh,      up, 20,  0, lane, uok);
    pgi1[0] = mkfrag(Wih, 20 + up, 49,  0, lane, uok);
    pgi1[1] = mkfrag(Wih, 20 + up, 49, 32, lane, uok);
    pgh1    = mkfrag(Whh, 20 + up, 20,  0, lane, uok);
    pgi2[0] = mkfrag(Wih, 40 + up, 49,  0, lane, uok);
    pgi2[1] = mkfrag(Wih, 40 + up, 49, 32, lane, uok);
    pgh2    = mkfrag(Whh, 40 + up, 20,  0, lane, uok);
    if (uok) {
      nbr = -C1 * (bih[up] + bhh[up]);
      nbz = -C1 * (bih[20 + up] + bhh[20 + up]);
      bin = bih[40 + up]; bhn = bhh[40 + up];
    }
    apB  = gru ? AP2  : AP1;
    aphB = gru ? AP2H : AP1H;
    gcol = gru ? (20 + up) : up;
    // staging map: item -> row rr, f32x2-col c2.
    //   c2 < 49: P-region (x_p1/x_p2), staged 1 phase ahead (parity (f+1)&1)
    //   49 <= c2 < 53: XG (xg cols of AG), staged same phase (parity f&1)
    //   c2 >= 53: XR (xr cols of AR), staged 1 phase LATE via xrHold (parity (f-1)&1)
#pragma unroll
    for (int it = 0; it < 3; ++it) {
      int ii = it * 256 + (pw * 64 + lane);
      stOK[it] = (ii < NITEMS);
      int iic = stOK[it] ? ii : (NITEMS - 1);
      ldIdx[it] = iic;
      int rr = iic / 66, c2 = iic % 66;
      clsXG[it] = (c2 >= 49) && (c2 < 53);
      clsXR[it] = (c2 >= 53);
      xrHold[it][0] = 0.0f; xrHold[it][1] = 0.0f;
#pragma unroll
      for (int e = 0; e < 2; ++e) {
        int c = c2 * 2 + e;
        int tb, col;
        if (c < 49)       { tb = AP1; col = c; }
        else if (c < 98)  { tb = AP2; col = c - 49; }
        else if (c < 106) { tb = AG;  col = 40 + (c - 98); }
        else              { tb = AR;  col = 16 + (c - 106); }
        stAddr[it][e] = tb + swz(rr, col);
      }
    }
  }

  __syncthreads();  // zeros visible

  // ---- prologue (p-waves): load x(0..3) into slots; P-stage x(0) -> par 0 ----
  f32x2 rs0[3], rs1[3], rs2[3], rs3[3];
  const f32x2* spR = nullptr;
  if (!isR) {
    const f32x2* sp = reinterpret_cast<const f32x2*>(seq) + (size_t)b0 * (D_IN / 2);
#pragma unroll
    for (int it = 0; it < 3; ++it) {
      rs0[it] = sp[ldIdx[it]];
      rs1[it] = sp[(size_t)1 * STEP2 + ldIdx[it]];
      rs2[it] = sp[(size_t)2 * STEP2 + ldIdx[it]];
      rs3[it] = sp[(size_t)3 * STEP2 + ldIdx[it]];
    }
#pragma unroll
    for (int it = 0; it < 3; ++it) if (stOK[it] && !clsXG[it] && !clsXR[it]) {
      lds[stAddr[it][0]] = (_Float16)rs0[it][0];
      lds[stAddr[it][1]] = (_Float16)rs0[it][1];
    }
    spR = sp + (size_t)4 * STEP2;
  }
  __syncthreads();

  // ---- r-waves, phase f: gate(t=f-1) at parity obf; main(t=f-2) at parity bfo ----
  auto rPhase = [&](int bfo, bool doGate, bool doMain) {
    const int obf = bfo ^ PX;
    if (doGate) {
      f16x8 g0 = ldsFrag(lds, AG + obf, lane, 0);
      f16x8 g1 = ldsFrag(lds, AG + obf, lane, 1);
      f32x4 cG = {0, 0, 0, 0};
      cG = MFMA16(g0, fgw[0], cG); cG = MFMA16(g1, fgw[1], cG);
      if (lane < 32) {
#pragma unroll
        for (int q = 0; q < 4; ++q) {
          float gv = fmaxf(cG[q] + gbias, 0.0f);
          lds[obf + arw[q]] = (_Float16)gv;
        }
      }
    }
    if (doMain) {
      f16x8 r0  = ldsFrag(lds, AR + bfo, lane, 0);
      f16x8 r1  = ldsFrag(lds, AR + bfo, lane, 1);
      f16x8 h0  = ldsFrag(lds, AH + obf, lane, 0);
      f16x8 h1f = ldsFrag(lds, AH + obf, lane, 1);
      f32x4 cR = {0, 0, 0, 0}, cZ = {0, 0, 0, 0}, cHN = {0, 0, 0, 0}, cIN = {0, 0, 0, 0};
      cR  = MFMA16(h0, fghr[0], cR);  cR  = MFMA16(h1f, fghr[1], cR);
      cZ  = MFMA16(h0, fghz[0], cZ);  cZ  = MFMA16(h1f, fghz[1], cZ);
      cHN = MFMA16(h0, fghn[0], cHN); cHN = MFMA16(h1f, fghn[1], cHN);
      cR  = MFMA16(r0, fgir[0], cR);  cR  = MFMA16(r1, fgir[1], cR);
      cZ  = MFMA16(r0, fgiz[0], cZ);  cZ  = MFMA16(r1, fgiz[1], cZ);
      cIN = MFMA16(r0, fgin[0], cIN); cIN = MFMA16(r1, fgin[1], cIN);
#pragma unroll
      for (int q = 0; q < 4; ++q) {
        float r   = rcpf(1.0f + ex2(fmaf(cR[q], -C1, nbr2)));
        float z   = rcpf(1.0f + ex2(fmaf(cZ[q], -C1, nbz2)));
        float pre = fmaf(r, cHN[q] + bhn2, cIN[q] + bin2);
        float e2  = ex2(pre * (2.0f * C1));
        float n   = 1.0f - 2.0f * rcpf(1.0f + e2);
        float hv  = fmaf(z, hq[q] - n, n);
        hq[q] = hv;
        if (lane < 32) {
          outp[(size_t)(rowb + q) * 64] = hv;
          lds[bfo + ahw[q]] = (_Float16)hv;
        }
      }
      outp += (size_t)B_BATCH * 64;
    }
  };

  // ---- p-waves, phase f (parity bfo=f&1): stage XG(f)@bfo, XR(f-1)@nbfo,
  //      P(f+1)@nbfo; load x(f+4); compute p-GRUs(t=f). ----
  auto pStep = [&](int bfo, bool act, bool stP, bool stXr, bool stXg,
                   bool doLoad, bool adv, f32x2 (&slotG)[3], f32x2 (&slotP)[3]) {
    const int nbfo = bfo ^ PX;
#pragma unroll
    for (int it = 0; it < 3; ++it) if (stOK[it]) {
      if (clsXG[it]) {
        if (stXg) {
          lds[bfo + stAddr[it][0]] = (_Float16)slotG[it][0];
          lds[bfo + stAddr[it][1]] = (_Float16)slotG[it][1];
        }
      } else if (clsXR[it]) {
        if (stXr) {
          lds[nbfo + stAddr[it][0]] = (_Float16)xrHold[it][0];
          lds[nbfo + stAddr[it][1]] = (_Float16)xrHold[it][1];
        }
        xrHold[it] = slotG[it];
      } else if (stP) {
        lds[nbfo + stAddr[it][0]] = (_Float16)slotP[it][0];
        lds[nbfo + stAddr[it][1]] = (_Float16)slotP[it][1];
      }
    }
    if (doLoad) {
#pragma unroll
      for (int it = 0; it < 3; ++it) slotG[it] = spR[ldIdx[it]];
      if (adv) spR += STEP2;
    }
    if (act) {
      f16x8 a0 = ldsFrag(lds, apB + bfo, lane, 0);
      f16x8 a1 = ldsFrag(lds, apB + bfo, lane, 1);
      f16x8 ah = ldsFrag(lds, aphB + bfo, lane, 0);
      f32x4 aR = {0, 0, 0, 0}, aZ = {0, 0, 0, 0}, aIN = {0, 0, 0, 0}, aHN = {0, 0, 0, 0};
      aR  = MFMA16(a0, pgi0[0], aR);  aR  = MFMA16(a1, pgi0[1], aR);  aR = MFMA16(ah, pgh0, aR);
      aZ  = MFMA16(a0, pgi1[0], aZ);  aZ  = MFMA16(a1, pgi1[1], aZ);  aZ = MFMA16(ah, pgh1, aZ);
      aIN = MFMA16(a0, pgi2[0], aIN); aIN = MFMA16(a1, pgi2[1], aIN);
      aHN = MFMA16(ah, pgh2, aHN);
      const bool wr = (lane < 32) && uok;
#pragma unroll
      for (int q = 0; q < 4; ++q) {
        float r   = rcpf(1.0f + ex2(fmaf(aR[q], -C1, nbr)));
        float z   = rcpf(1.0f + ex2(fmaf(aZ[q], -C1, nbz)));
        float pre = fmaf(r, aHN[q] + bhn, aIN[q] + bin);
        float e2  = ex2(pre * (2.0f * C1));
        float n   = 1.0f - 2.0f * rcpf(1.0f + e2);
        float hv  = fmaf(z, h1q[q] - n, n);
        h1q[q] = hv;
        if (wr) {
          _Float16 hh = (_Float16)hv;
          lds[AG + bfo + swz(rowb + q, gcol)]  = hh;   // gate input, read next phase
          lds[aphB + nbfo + swz(rowb + q, up)] = hh;   // own h-path, next phase
        }
      }
    }
  };

  // ---- main loop: phases f = 4i+j, j=0..3; i in [0,127] -> f in [0,511] ----
  for (int i = 0; i < T_STEPS / 4; ++i) {
    const bool i0 = (i == 0);
    // f = 4i (even, bfo=0)
    if (isR) rPhase(0, !i0, !i0);
    else     pStep(0, true, true, !i0, true, true, (4*i + 5 < T_STEPS), rs0, rs1);
    BARRIER();
    // f = 4i+1 (odd, bfo=PX)
    if (isR) rPhase(PX, true, !i0);
    else     pStep(PX, true, true, true, true, true, (4*i + 6 < T_STEPS), rs1, rs2);
    BARRIER();
    // f = 4i+2 (even)
    if (isR) rPhase(0, true, true);
    else     pStep(0, true, true, true, true, true, (4*i + 7 < T_STEPS), rs2, rs3);
    BARRIER();
    // f = 4i+3 (odd)
    if (isR) rPhase(PX, true, true);
    else     pStep(PX, true, (i != T_STEPS/4 - 1), true, true, true, (4*i + 8 < T_STEPS), rs3, rs0);
    BARRIER();
  }
  // ---- epilogue: f=512 (even): gate(511) + main(510); p stages xr(511) ----
  if (isR) rPhase(0, true, true);
  else     pStep(0, false, false, true, false, false, false, rs0, rs1);
  BARRIER();
  // ---- f=513 (odd): main(511) ----
  if (isR) rPhase(PX, false, true);
}

extern "C" void kernel_launch(void* const* d_in, const int* in_sizes, int n_in,
                              void* d_out, int out_size, void* d_ws, size_t ws_size,
                              hipStream_t stream) {
  (void)in_sizes; (void)n_in; (void)d_ws; (void)ws_size; (void)out_size;
  const float* seq   = (const float*)d_in[0];
  const float* p1Wih = (const float*)d_in[1];
  const float* p1Whh = (const float*)d_in[2];
  const float* p1bih = (const float*)d_in[3];
  const float* p1bhh = (const float*)d_in[4];
  const float* p2Wih = (const float*)d_in[5];
  const float* p2Whh = (const float*)d_in[6];
  const float* p2bih = (const float*)d_in[7];
  const float* p2bhh = (const float*)d_in[8];
  const float* gW    = (const float*)d_in[9];
  const float* gb    = (const float*)d_in[10];
  const float* rWih  = (const float*)d_in[11];
  const float* rWhh  = (const float*)d_in[12];
  const float* rbih  = (const float*)d_in[13];
  const float* rbhh  = (const float*)d_in[14];
  float* out = (float*)d_out;
  hipLaunchKernelGGL(rnn_fused, dim3(NBLOCKS), dim3(512), 0, stream,
                     seq, p1Wih, p1Whh, p1bih, p1bhh,
                     p2Wih, p2Whh, p2bih, p2bhh,
                     gW, gb, rWih, rWhh, rbih, rbhh, out);
}

// Round 10
// 374.494 us; speedup vs baseline: 1.2768x; 1.2768x over previous
//
#include <hip/hip_runtime.h>

// Fused persistent stacked-GRU kernel for MI355X (gfx950).
// Round-10: 3-stage pipeline with GATE ON P-WAVES, one lean barrier/phase,
// zero intra-phase LDS round-trips.
//   phase f: r-waves: stage x(f+1), prefetch x(f+4), main-GRU(t=f-2)
//            p-waves: p1/p2-GRUs(t=f), gate(t=f-1)
// Handoffs (all cross >=1 barrier; slot rings sized so writers never touch
// a slot a reader still needs):
//   AP[2]:  x_p(t) staged @f=t-1, read by p @f=t
//   AG[4]:  h1h2(t) @f=t (p), xg(t) staged @f=t-1 (r), read by gate @f=t+1
//   AR[4]:  xr(t) staged @f=t-1 (r), gate(t) @f=t+1 (p), read by main @f=t+2
//   APH[2]: h1h2(t) @f=t, read by p @f=t+1
//   AH[2]:  h(t) @f=t+2 (r), read by main(t+1) @f=t+3
// 256 blocks x 8 rows, launch_bounds(512,2) (VGPR~100, no spill).

#define T_STEPS 512
#define B_BATCH 2048
#define D_IN    132
#define NROWS   8
#define NBLOCKS 256
#define STEP2   (B_BATCH * D_IN / 2)   // f32x2 per timestep
#define NITEMS  (NROWS * 66)           // 528 f32x2 per step per block

typedef _Float16 f16x8 __attribute__((ext_vector_type(8)));
typedef float    f32x4 __attribute__((ext_vector_type(4)));
typedef float    f32x2 __attribute__((ext_vector_type(2)));

#define MFMA16(a, b, c) __builtin_amdgcn_mfma_f32_16x16x32_f16((a), (b), (c), 0, 0, 0)

// LDS tiles [16 rows][64 cols] fp16 = 1024 elems each; PX = slot stride.
#define PX    1024
#define AP1   0      // x_p1 cols 0..48                  (2 slots)
#define AP2   2048   // x_p2 cols 0..48                  (2 slots)
#define AG    4096   // h1:0-19 h2:20-39 xg:40-47        (4 slots)
#define AR    8192   // gate:0-15 xr:16-41               (4 slots)
#define AP1H  12288  // h1 cols 0..19                    (2 slots)
#define AP2H  14336  // h2 cols 0..19                    (2 slots)
#define AH    16384  // h cols 0..63                     (2 slots)
#define LDS_N 18432

// Raw barrier: LDS visibility only (lgkmcnt), NO vmcnt drain -> HBM prefetch
// stays in flight across barriers. seq read-only, out write-only.
#define BARRIER() do { \
    asm volatile("s_waitcnt lgkmcnt(0)\n\ts_barrier" ::: "memory"); \
    __builtin_amdgcn_sched_barrier(0); \
  } while (0)

__device__ __forceinline__ int swz(int row, int col) {
  return row * 64 + (((col >> 3) ^ (row & 7)) << 3) + (col & 7);
}

__device__ __forceinline__ f16x8 ldsFrag(const _Float16* lds, int base, int lane, int kt) {
  int row = lane & 15;
  int blk = ((kt << 2) + (lane >> 4)) ^ (row & 7);
  return *reinterpret_cast<const f16x8*>(lds + base + row * 64 + blk * 8);
}

__device__ __forceinline__ f16x8 mkfrag(const float* W, int row, int K, int kbase, int lane, bool ok) {
  f16x8 f;
  int k0 = kbase + ((lane >> 4) << 3);
#pragma unroll
  for (int j = 0; j < 8; ++j) {
    int k = k0 + j;
    float v = 0.0f;
    if (ok && k < K) v = W[row * K + k];
    f[j] = (_Float16)v;
  }
  return f;
}

__device__ __forceinline__ float rcpf(float x) { return __builtin_amdgcn_rcpf(x); }
__device__ __forceinline__ float ex2(float x)  { return __builtin_amdgcn_exp2f(x); }

__global__ __launch_bounds__(512, 2) void rnn_fused(
    const float* __restrict__ seq,
    const float* __restrict__ p1Wih, const float* __restrict__ p1Whh,
    const float* __restrict__ p1bih, const float* __restrict__ p1bhh,
    const float* __restrict__ p2Wih, const float* __restrict__ p2Whh,
    const float* __restrict__ p2bih, const float* __restrict__ p2bhh,
    const float* __restrict__ gW,    const float* __restrict__ gb,
    const float* __restrict__ rWih,  const float* __restrict__ rWhh,
    const float* __restrict__ rbih,  const float* __restrict__ rbhh,
    float* __restrict__ out)
{
  __shared__ __align__(16) _Float16 lds[LDS_N];
  const int tid  = threadIdx.x;
  const int lane = tid & 63;
  const int wv   = tid >> 6;
  const bool isR = (wv < 4);
  const int b0   = blockIdx.x * NROWS;
  const int ul   = lane & 15;
  const int rowb = (lane >> 4) * 4;
  const float C1 = 1.44269504089f;

  for (int i = tid; i < LDS_N; i += 512) lds[i] = (_Float16)0.0f;

  // ---------------- r-wave state (staging + main GRU) ----------------
  f16x8 fghr[2], fghz[2], fghn[2], fgir[2], fgiz[2], fgin[2];
  float nbr2 = 0, nbz2 = 0, bin2 = 0, bhn2 = 0;
  float hq[4] = {0, 0, 0, 0};
  int stAddr[3][2]; int ldIdx[3] = {0, 0, 0};
  bool stOK[3] = {false, false, false}, isP[3] = {false, false, false};
  int uR = 0, ahw[4] = {0, 0, 0, 0};
  float* outp = nullptr;

  // ---------------- p-wave state (p-GRUs + gate) ----------------
  f16x8 pgi0[2], pgi1[2], pgi2[2], pgh0, pgh1, pgh2, fgw[2];
  float nbr = 0, nbz = 0, bin = 0, bhn = 0, gbias = 0;
  float h1q[4] = {0, 0, 0, 0};
  int apB = 0, aphB = 0, up = 0; bool uok = false;
  int agw[4] = {0, 0, 0, 0}, aphw[4] = {0, 0, 0, 0}, arw[4] = {0, 0, 0, 0};

  if (isR) {
    uR = wv * 16 + ul;
    fghr[0] = mkfrag(rWhh,       uR, 64,  0, lane, true);
    fghr[1] = mkfrag(rWhh,       uR, 64, 32, lane, true);
    fghz[0] = mkfrag(rWhh,  64 + uR, 64,  0, lane, true);
    fghz[1] = mkfrag(rWhh,  64 + uR, 64, 32, lane, true);
    fghn[0] = mkfrag(rWhh, 128 + uR, 64,  0, lane, true);
    fghn[1] = mkfrag(rWhh, 128 + uR, 64, 32, lane, true);
    fgir[0] = mkfrag(rWih,       uR, 42,  0, lane, true);
    fgir[1] = mkfrag(rWih,       uR, 42, 32, lane, true);
    fgiz[0] = mkfrag(rWih,  64 + uR, 42,  0, lane, true);
    fgiz[1] = mkfrag(rWih,  64 + uR, 42, 32, lane, true);
    fgin[0] = mkfrag(rWih, 128 + uR, 42,  0, lane, true);
    fgin[1] = mkfrag(rWih, 128 + uR, 42, 32, lane, true);
    nbr2 = -C1 * (rbih[uR] + rbhh[uR]);
    nbz2 = -C1 * (rbih[64 + uR] + rbhh[64 + uR]);
    bin2 = rbih[128 + uR]; bhn2 = rbhh[128 + uR];
#pragma unroll
    for (int q = 0; q < 4; ++q) ahw[q] = AH + swz(rowb + q, uR);
    // staging map: 528 f32x2 items over 256 r-threads, 3 item-slots
#pragma unroll
    for (int it = 0; it < 3; ++it) {
      int ii = it * 256 + (wv * 64 + lane);
      stOK[it] = (ii < NITEMS);
      int iic = stOK[it] ? ii : (NITEMS - 1);
      ldIdx[it] = iic;
      int rr = iic / 66, c2 = iic % 66;
      isP[it] = (c2 < 49);
#pragma unroll
      for (int e = 0; e < 2; ++e) {
        int c = c2 * 2 + e;
        int tb, col;
        if (c < 49)       { tb = AP1; col = c; }
        else if (c < 98)  { tb = AP2; col = c - 49; }
        else if (c < 106) { tb = AG;  col = 40 + (c - 98); }
        else              { tb = AR;  col = 16 + (c - 106); }
        stAddr[it][e] = tb + swz(rr, col);
      }
    }
    outp = out + (size_t)b0 * 64 + uR;
  } else {
    const int pw  = wv - 4;
    const int gru = pw >> 1;
    const int s   = pw & 1;
    const float* Wih = gru ? p2Wih : p1Wih;
    const float* Whh = gru ? p2Whh : p1Whh;
    const float* bih = gru ? p2bih : p1bih;
    const float* bhh = gru ? p2bhh : p1bhh;
    up  = s * 16 + ul;
    uok = (up < 20);
    pgi0[0] = mkfrag(Wih,      up, 49,  0, lane, uok);
    pgi0[1] = mkfrag(Wih,      up, 49, 32, lane, uok);
    pgh0    = mkfrag(Whh,      up, 20,  0, lane, uok);
    pgi1[0] = mkfrag(Wih, 20 + up, 49,  0, lane, uok);
    pgi1[1] = mkfrag(Wih, 20 + up, 49, 32, lane, uok);
    pgh1    = mkfrag(Whh, 20 + up, 20,  0, lane, uok);
    pgi2[0] = mkfrag(Wih, 40 + up, 49,  0, lane, uok);
    pgi2[1] = mkfrag(Wih, 40 + up, 49, 32, lane, uok);
    pgh2    = mkfrag(Whh, 40 + up, 20,  0, lane, uok);
    fgw[0]  = mkfrag(gW, ul, 48,  0, lane, true);
    fgw[1]  = mkfrag(gW, ul, 48, 32, lane, true);
    gbias = gb[ul];
    if (uok) {
      nbr = -C1 * (bih[up] + bhh[up]);
      nbz = -C1 * (bih[20 + up] + bhh[20 + up]);
      bin = bih[40 + up]; bhn = bhh[40 + up];
    }
    apB  = gru ? AP2  : AP1;
    aphB = gru ? AP2H : AP1H;
    const int gcol = gru ? (20 + up) : up;
#pragma unroll
    for (int q = 0; q < 4; ++q) {
      agw[q]  = AG + swz(rowb + q, gcol);
      aphw[q] = aphB + swz(rowb + q, up);
      arw[q]  = AR + swz(rowb + q, ul);
    }
  }

  __syncthreads();  // zeros visible

  // ---- prologue (r-waves): load x(0..3) into 4 slots; stage x(0) -> slot 0 ----
  f32x2 rs0[3], rs1[3], rs2[3], rs3[3];
  const f32x2* spR = nullptr;
  if (isR) {
    const f32x2* sp = reinterpret_cast<const f32x2*>(seq) + (size_t)b0 * (D_IN / 2);
#pragma unroll
    for (int it = 0; it < 3; ++it) {
      rs0[it] = sp[ldIdx[it]];
      rs1[it] = sp[(size_t)1 * STEP2 + ldIdx[it]];
      rs2[it] = sp[(size_t)2 * STEP2 + ldIdx[it]];
      rs3[it] = sp[(size_t)3 * STEP2 + ldIdx[it]];
    }
#pragma unroll
    for (int it = 0; it < 3; ++it) if (stOK[it]) {
      lds[stAddr[it][0]] = (_Float16)rs0[it][0];   // all classes -> slot 0
      lds[stAddr[it][1]] = (_Float16)rs0[it][1];
    }
    spR = sp + (size_t)4 * STEP2;
  }
  __syncthreads();

  // ---- r-wave phase f: stage x(f+1), prefetch x(f+4), main(t=f-2) ----
  // offP = ((f+1)&1)*PX, offGR = ((f+1)&3)*PX, slotA = ((f-2)&3)*PX,
  // ahR = ((f+1)&1)*PX, ahW = (f&1)*PX
  auto rPhase = [&](int offP, int offGR, int slotA, int ahR, int ahW,
                    bool doMain, bool doStage, f32x2 (&rsStage)[3], f32x2 (&rsLoad)[3],
                    bool advance) {
    // prefetch x(min(f+4,511)); stays in flight past barriers
#pragma unroll
    for (int it = 0; it < 3; ++it) rsLoad[it] = spR[ldIdx[it]];
    if (advance) spR += STEP2;
    if (doStage) {
#pragma unroll
      for (int it = 0; it < 3; ++it) if (stOK[it]) {
        const int off = isP[it] ? offP : offGR;
        lds[off + stAddr[it][0]] = (_Float16)rsStage[it][0];
        lds[off + stAddr[it][1]] = (_Float16)rsStage[it][1];
      }
    }
    if (doMain) {
      f16x8 r0  = ldsFrag(lds, AR + slotA, lane, 0);
      f16x8 r1  = ldsFrag(lds, AR + slotA, lane, 1);
      f16x8 h0  = ldsFrag(lds, AH + ahR, lane, 0);
      f16x8 h1f = ldsFrag(lds, AH + ahR, lane, 1);
      f32x4 cR = {0, 0, 0, 0}, cZ = {0, 0, 0, 0}, cHN = {0, 0, 0, 0}, cIN = {0, 0, 0, 0};
      cR  = MFMA16(h0, fghr[0], cR);  cR  = MFMA16(h1f, fghr[1], cR);
      cZ  = MFMA16(h0, fghz[0], cZ);  cZ  = MFMA16(h1f, fghz[1], cZ);
      cHN = MFMA16(h0, fghn[0], cHN); cHN = MFMA16(h1f, fghn[1], cHN);
      cR  = MFMA16(r0, fgir[0], cR);  cR  = MFMA16(r1, fgir[1], cR);
      cZ  = MFMA16(r0, fgiz[0], cZ);  cZ  = MFMA16(r1, fgiz[1], cZ);
      cIN = MFMA16(r0, fgin[0], cIN); cIN = MFMA16(r1, fgin[1], cIN);
#pragma unroll
      for (int q = 0; q < 4; ++q) {
        float r   = rcpf(1.0f + ex2(fmaf(cR[q], -C1, nbr2)));
        float z   = rcpf(1.0f + ex2(fmaf(cZ[q], -C1, nbz2)));
        float pre = fmaf(r, cHN[q] + bhn2, cIN[q] + bin2);
        float e2  = ex2(pre * (2.0f * C1));
        float n   = 1.0f - 2.0f * rcpf(1.0f + e2);
        float hv  = fmaf(z, hq[q] - n, n);
        hq[q] = hv;
        if (lane < 32) {
          outp[(size_t)(rowb + q) * 64] = hv;
          lds[ahW + ahw[q]] = (_Float16)hv;
        }
      }
      outp += (size_t)B_BATCH * 64;
    }
  };

  // ---- p-wave phase f: p-GRUs(t=f) + gate(t=f-1) ----
  // pj = (f&1)*PX, agWr = (f&3)*PX, aphWr = ((f+1)&1)*PX, gSlot = ((f-1)&3)*PX
  auto pPhase = [&](int pj, int agWr, int aphWr, int gSlot, bool doComp, bool doGate) {
    if (doComp) {
      f16x8 a0 = ldsFrag(lds, apB + pj, lane, 0);
      f16x8 a1 = ldsFrag(lds, apB + pj, lane, 1);
      f16x8 ah = ldsFrag(lds, aphB + pj, lane, 0);
      f32x4 aR = {0, 0, 0, 0}, aZ = {0, 0, 0, 0}, aIN = {0, 0, 0, 0}, aHN = {0, 0, 0, 0};
      aR  = MFMA16(a0, pgi0[0], aR);  aR  = MFMA16(a1, pgi0[1], aR);  aR = MFMA16(ah, pgh0, aR);
      aZ  = MFMA16(a0, pgi1[0], aZ);  aZ  = MFMA16(a1, pgi1[1], aZ);  aZ = MFMA16(ah, pgh1, aZ);
      aIN = MFMA16(a0, pgi2[0], aIN); aIN = MFMA16(a1, pgi2[1], aIN);
      aHN = MFMA16(ah, pgh2, aHN);
      const bool wr = (lane < 32) && uok;
#pragma unroll
      for (int q = 0; q < 4; ++q) {
        float r   = rcpf(1.0f + ex2(fmaf(aR[q], -C1, nbr)));
        float z   = rcpf(1.0f + ex2(fmaf(aZ[q], -C1, nbz)));
        float pre = fmaf(r, aHN[q] + bhn, aIN[q] + bin);
        float e2  = ex2(pre * (2.0f * C1));
        float n   = 1.0f - 2.0f * rcpf(1.0f + e2);
        float hv  = fmaf(z, h1q[q] - n, n);
        h1q[q] = hv;
        if (wr) {
          _Float16 hh = (_Float16)hv;
          lds[agWr + agw[q]]  = hh;   // -> AG slot f&3 (gate input, read @f+1)
          lds[aphWr + aphw[q]] = hh;  // -> own h-path, read @f+1
        }
      }
    }
    if (doGate) {
      f16x8 g0 = ldsFrag(lds, AG + gSlot, lane, 0);
      f16x8 g1 = ldsFrag(lds, AG + gSlot, lane, 1);
      f32x4 cG = {0, 0, 0, 0};
      cG = MFMA16(g0, fgw[0], cG); cG = MFMA16(g1, fgw[1], cG);
      if (lane < 32) {
#pragma unroll
        for (int q = 0; q < 4; ++q) {
          float gv = fmaxf(cG[q] + gbias, 0.0f);
          lds[gSlot + arw[q]] = (_Float16)gv;   // AR slot (f-1)&3, read @f+1
        }
      }
    }
  };

  // ---- main loop: f = 4i+j, i in [0,127], j in [0,3] ----
  for (int i = 0; i < T_STEPS / 4; ++i) {
    const bool i0 = (i == 0);
    const int f0 = 4 * i;
    // j=0: offP=PX offGR=PX slotA=2PX ahR=PX ahW=0 | p: pj=0 agWr=0 aphWr=PX gSlot=3PX
    if (isR) rPhase(PX, PX, 2 * PX, PX, 0, !i0, true, rs1, rs0, (f0 + 5 < T_STEPS));
    else     pPhase(0, 0, PX, 3 * PX, true, !i0);
    BARRIER();
    // j=1: offP=0 offGR=2PX slotA=3PX ahR=0 ahW=PX | p: pj=PX agWr=PX aphWr=0 gSlot=0
    if (isR) rPhase(0, 2 * PX, 3 * PX, 0, PX, !i0, true, rs2, rs1, (f0 + 6 < T_STEPS));
    else     pPhase(PX, PX, 0, 0, true, true);
    BARRIER();
    // j=2: offP=PX offGR=3PX slotA=0 ahR=PX ahW=0 | p: pj=0 agWr=2PX aphWr=PX gSlot=PX
    if (isR) rPhase(PX, 3 * PX, 0, PX, 0, true, true, rs3, rs2, (f0 + 7 < T_STEPS));
    else     pPhase(0, 2 * PX, PX, PX, true, true);
    BARRIER();
    // j=3: offP=0 offGR=0 slotA=PX ahR=0 ahW=PX | p: pj=PX agWr=3PX aphWr=0 gSlot=2PX
    if (isR) rPhase(0, 0, PX, 0, PX, true, (i != T_STEPS / 4 - 1), rs0, rs3,
                    (f0 + 8 < T_STEPS));
    else     pPhase(PX, 3 * PX, 0, 2 * PX, true, true);
    BARRIER();
  }
  // ---- epilogue: f=512 (even): main(510) slotA=(510&3)=2PX ahR=PX ahW=0;
  //      p: gate(511) gSlot=3PX ----
  if (isR) rPhase(0, 0, 2 * PX, PX, 0, true, false, rs0, rs1, false);
  else     pPhase(0, 0, PX, 3 * PX, false, true);
  BARRIER();
  // ---- f=513 (odd): main(511) slotA=(511&3)=3PX ahR=0 ahW=PX ----
  if (isR) rPhase(0, 0, 3 * PX, 0, PX, true, false, rs0, rs1, false);
}

extern "C" void kernel_launch(void* const* d_in, const int* in_sizes, int n_in,
                              void* d_out, int out_size, void* d_ws, size_t ws_size,
                              hipStream_t stream) {
  (void)in_sizes; (void)n_in; (void)d_ws; (void)ws_size; (void)out_size;
  const float* seq   = (const float*)d_in[0];
  const float* p1Wih = (const float*)d_in[1];
  const float* p1Whh = (const float*)d_in[2];
  const float* p1bih = (const float*)d_in[3];
  const float* p1bhh = (const float*)d_in[4];
  const float* p2Wih = (const float*)d_in[5];
  const float* p2Whh = (const float*)d_in[6];
  const float* p2bih = (const float*)d_in[7];
  const float* p2bhh = (const float*)d_in[8];
  const float* gW    = (const float*)d_in[9];
  const float* gb    = (const float*)d_in[10];
  const float* rWih  = (const float*)d_in[11];
  const float* rWhh  = (const float*)d_in[12];
  const float* rbih  = (const float*)d_in[13];
  const float* rbhh  = (const float*)d_in[14];
  float* out = (float*)d_out;
  hipLaunchKernelGGL(rnn_fused, dim3(NBLOCKS), dim3(512), 0, stream,
                     seq, p1Wih, p1Whh, p1bih, p1bhh,
                     p2Wih, p2Whh, p2bih, p2bhh,
                     gW, gb, rWih, rWhh, rbih, rbhh, out);
}

// Round 11
// 350.896 us; speedup vs baseline: 1.3627x; 1.0672x over previous
//
#include <hip/hip_runtime.h>

// Fused persistent stacked-GRU kernel for MI355X (gfx950).
// Round-11: R10 3-stage pipeline (p||gate||main, gate on p-waves, 1 lean
// barrier/phase) + ACTIVATION LANE-REDISTRIBUTION: with NROWS=8 only lanes
// 0-31 hold real MFMA C-rows; broadcast acc q=2,3 to lanes 32-63 (shfl) so
// every lane computes 2 activations instead of 4 -> per-wave transcendental
// issue halves. Arithmetic bit-identical; writes become 2/lane on all lanes.
// 256 blocks x 8 rows, launch_bounds(512,2).

#define T_STEPS 512
#define B_BATCH 2048
#define D_IN    132
#define NROWS   8
#define NBLOCKS 256
#define STEP2   (B_BATCH * D_IN / 2)   // f32x2 per timestep
#define NITEMS  (NROWS * 66)           // 528 f32x2 per step per block

typedef _Float16 f16x8 __attribute__((ext_vector_type(8)));
typedef float    f32x4 __attribute__((ext_vector_type(4)));
typedef float    f32x2 __attribute__((ext_vector_type(2)));

#define MFMA16(a, b, c) __builtin_amdgcn_mfma_f32_16x16x32_f16((a), (b), (c), 0, 0, 0)

// LDS tiles [16 rows][64 cols] fp16 = 1024 elems each; PX = slot stride.
#define PX    1024
#define AP1   0      // x_p1 cols 0..48                  (2 slots)
#define AP2   2048   // x_p2 cols 0..48                  (2 slots)
#define AG    4096   // h1:0-19 h2:20-39 xg:40-47        (4 slots)
#define AR    8192   // gate:0-15 xr:16-41               (4 slots)
#define AP1H  12288  // h1 cols 0..19                    (2 slots)
#define AP2H  14336  // h2 cols 0..19                    (2 slots)
#define AH    16384  // h cols 0..63                     (2 slots)
#define LDS_N 18432

// Raw barrier: LDS visibility only (lgkmcnt), NO vmcnt drain -> HBM prefetch
// stays in flight across barriers. seq read-only, out write-only.
#define BARRIER() do { \
    asm volatile("s_waitcnt lgkmcnt(0)\n\ts_barrier" ::: "memory"); \
    __builtin_amdgcn_sched_barrier(0); \
  } while (0)

__device__ __forceinline__ int swz(int row, int col) {
  return row * 64 + (((col >> 3) ^ (row & 7)) << 3) + (col & 7);
}

__device__ __forceinline__ f16x8 ldsFrag(const _Float16* lds, int base, int lane, int kt) {
  int row = lane & 15;
  int blk = ((kt << 2) + (lane >> 4)) ^ (row & 7);
  return *reinterpret_cast<const f16x8*>(lds + base + row * 64 + blk * 8);
}

__device__ __forceinline__ f16x8 mkfrag(const float* W, int row, int K, int kbase, int lane, bool ok) {
  f16x8 f;
  int k0 = kbase + ((lane >> 4) << 3);
#pragma unroll
  for (int j = 0; j < 8; ++j) {
    int k = k0 + j;
    float v = 0.0f;
    if (ok && k < K) v = W[row * K + k];
    f[j] = (_Float16)v;
  }
  return f;
}

__device__ __forceinline__ float rcpf(float x) { return __builtin_amdgcn_rcpf(x); }
__device__ __forceinline__ float ex2(float x)  { return __builtin_amdgcn_exp2f(x); }

__global__ __launch_bounds__(512, 2) void rnn_fused(
    const float* __restrict__ seq,
    const float* __restrict__ p1Wih, const float* __restrict__ p1Whh,
    const float* __restrict__ p1bih, const float* __restrict__ p1bhh,
    const float* __restrict__ p2Wih, const float* __restrict__ p2Whh,
    const float* __restrict__ p2bih, const float* __restrict__ p2bhh,
    const float* __restrict__ gW,    const float* __restrict__ gb,
    const float* __restrict__ rWih,  const float* __restrict__ rWhh,
    const float* __restrict__ rbih,  const float* __restrict__ rbhh,
    float* __restrict__ out)
{
  __shared__ __align__(16) _Float16 lds[LDS_N];
  const int tid  = threadIdx.x;
  const int lane = tid & 63;
  const int wv   = tid >> 6;
  const bool isR = (wv < 4);
  const int b0   = blockIdx.x * NROWS;
  const int ul   = lane & 15;
  const int l31  = lane & 31;
  const bool lo  = (lane < 32);
  // redistribution row mapping: lanes<32 -> rows grp4+{0,1}; lanes>=32 -> grp4+{2,3}
  const int grp4 = ((lane >> 4) & 1) * 4;
  const int row0 = grp4 + (lo ? 0 : 2);
  const float C1 = 1.44269504089f;

  for (int i = tid; i < LDS_N; i += 512) lds[i] = (_Float16)0.0f;

  // ---------------- r-wave state (staging + main GRU) ----------------
  f16x8 fghr[2], fghz[2], fghn[2], fgir[2], fgiz[2], fgin[2];
  float nbr2 = 0, nbz2 = 0, bin2 = 0, bhn2 = 0;
  float hq2[2] = {0, 0};
  int stAddr[3][2]; int ldIdx[3] = {0, 0, 0};
  bool stOK[3] = {false, false, false}, isP[3] = {false, false, false};
  int ahw2[2] = {0, 0};
  float* outp = nullptr;

  // ---------------- p-wave state (p-GRUs + gate) ----------------
  f16x8 pgi0[2], pgi1[2], pgi2[2], pgh0, pgh1, pgh2, fgw[2];
  float nbr = 0, nbz = 0, bin = 0, bhn = 0, gbias = 0;
  float h1q2[2] = {0, 0};
  int apB = 0, aphB = 0, up = 0; bool uok = false;
  int agw2[2] = {0, 0}, aphw2[2] = {0, 0}, arw2[2] = {0, 0};

  if (isR) {
    const int uR = wv * 16 + ul;
    fghr[0] = mkfrag(rWhh,       uR, 64,  0, lane, true);
    fghr[1] = mkfrag(rWhh,       uR, 64, 32, lane, true);
    fghz[0] = mkfrag(rWhh,  64 + uR, 64,  0, lane, true);
    fghz[1] = mkfrag(rWhh,  64 + uR, 64, 32, lane, true);
    fghn[0] = mkfrag(rWhh, 128 + uR, 64,  0, lane, true);
    fghn[1] = mkfrag(rWhh, 128 + uR, 64, 32, lane, true);
    fgir[0] = mkfrag(rWih,       uR, 42,  0, lane, true);
    fgir[1] = mkfrag(rWih,       uR, 42, 32, lane, true);
    fgiz[0] = mkfrag(rWih,  64 + uR, 42,  0, lane, true);
    fgiz[1] = mkfrag(rWih,  64 + uR, 42, 32, lane, true);
    fgin[0] = mkfrag(rWih, 128 + uR, 42,  0, lane, true);
    fgin[1] = mkfrag(rWih, 128 + uR, 42, 32, lane, true);
    nbr2 = -C1 * (rbih[uR] + rbhh[uR]);
    nbz2 = -C1 * (rbih[64 + uR] + rbhh[64 + uR]);
    bin2 = rbih[128 + uR]; bhn2 = rbhh[128 + uR];
    ahw2[0] = AH + swz(row0, uR);
    ahw2[1] = AH + swz(row0 + 1, uR);
    // staging map: 528 f32x2 items over 256 r-threads, 3 item-slots
#pragma unroll
    for (int it = 0; it < 3; ++it) {
      int ii = it * 256 + (wv * 64 + lane);
      stOK[it] = (ii < NITEMS);
      int iic = stOK[it] ? ii : (NITEMS - 1);
      ldIdx[it] = iic;
      int rr = iic / 66, c2 = iic % 66;
      isP[it] = (c2 < 49);
#pragma unroll
      for (int e = 0; e < 2; ++e) {
        int c = c2 * 2 + e;
        int tb, col;
        if (c < 49)       { tb = AP1; col = c; }
        else if (c < 98)  { tb = AP2; col = c - 49; }
        else if (c < 106) { tb = AG;  col = 40 + (c - 98); }
        else              { tb = AR;  col = 16 + (c - 106); }
        stAddr[it][e] = tb + swz(rr, col);
      }
    }
    outp = out + (size_t)(b0 + row0) * 64 + uR;
  } else {
    const int pw  = wv - 4;
    const int gru = pw >> 1;
    const int s   = pw & 1;
    const float* Wih = gru ? p2Wih : p1Wih;
    const float* Whh = gru ? p2Whh : p1Whh;
    const float* bih = gru ? p2bih : p1bih;
    const float* bhh = gru ? p2bhh : p1bhh;
    up  = s * 16 + ul;
    uok = (up < 20);
    pgi0[0] = mkfrag(Wih,      up, 49,  0, lane, uok);
    pgi0[1] = mkfrag(Wih,      up, 49, 32, lane, uok);
    pgh0    = mkfrag(Whh,      up, 20,  0, lane, uok);
    pgi1[0] = mkfrag(Wih, 20 + up, 49,  0, lane, uok);
    pgi1[1] = mkfrag(Wih, 20 + up, 49, 32, lane, uok);
    pgh1    = mkfrag(Whh, 20 + up, 20,  0, lane, uok);
    pgi2[0] = mkfrag(Wih, 40 + up, 49,  0, lane, uok);
    pgi2[1] = mkfrag(Wih, 40 + up, 49, 32, lane, uok);
    pgh2    = mkfrag(Whh, 40 + up, 20,  0, lane, uok);
    fgw[0]  = mkfrag(gW, ul, 48,  0, lane, true);
    fgw[1]  = mkfrag(gW, ul, 48, 32, lane, true);
    gbias = gb[ul];
    if (uok) {
      nbr = -C1 * (bih[up] + bhh[up]);
      nbz = -C1 * (bih[20 + up] + bhh[20 + up]);
      bin = bih[40 + up]; bhn = bhh[40 + up];
    }
    apB  = gru ? AP2  : AP1;
    aphB = gru ? AP2H : AP1H;
    const int gcol = gru ? (20 + up) : up;
#pragma unroll
    for (int j = 0; j < 2; ++j) {
      agw2[j]  = AG + swz(row0 + j, gcol);
      aphw2[j] = aphB + swz(row0 + j, up);
      arw2[j]  = AR + swz(row0 + j, ul);
    }
  }

  __syncthreads();  // zeros visible

  // ---- prologue (r-waves): load x(0..3) into 4 slots; stage x(0) -> slot 0 ----
  f32x2 rs0[3], rs1[3], rs2[3], rs3[3];
  const f32x2* spR = nullptr;
  if (isR) {
    const f32x2* sp = reinterpret_cast<const f32x2*>(seq) + (size_t)b0 * (D_IN / 2);
#pragma unroll
    for (int it = 0; it < 3; ++it) {
      rs0[it] = sp[ldIdx[it]];
      rs1[it] = sp[(size_t)1 * STEP2 + ldIdx[it]];
      rs2[it] = sp[(size_t)2 * STEP2 + ldIdx[it]];
      rs3[it] = sp[(size_t)3 * STEP2 + ldIdx[it]];
    }
#pragma unroll
    for (int it = 0; it < 3; ++it) if (stOK[it]) {
      lds[stAddr[it][0]] = (_Float16)rs0[it][0];   // all classes -> slot 0
      lds[stAddr[it][1]] = (_Float16)rs0[it][1];
    }
    spR = sp + (size_t)4 * STEP2;
  }
  __syncthreads();

  // ---- r-wave phase f: stage x(f+1), prefetch x(f+4), main(t=f-2) ----
  auto rPhase = [&](int offP, int offGR, int slotA, int ahR, int ahW,
                    bool doMain, bool doStage, f32x2 (&rsStage)[3], f32x2 (&rsLoad)[3],
                    bool advance) {
    // prefetch x(min(f+4,511)); stays in flight past barriers
#pragma unroll
    for (int it = 0; it < 3; ++it) rsLoad[it] = spR[ldIdx[it]];
    if (advance) spR += STEP2;
    if (doStage) {
#pragma unroll
      for (int it = 0; it < 3; ++it) if (stOK[it]) {
        const int off = isP[it] ? offP : offGR;
        lds[off + stAddr[it][0]] = (_Float16)rsStage[it][0];
        lds[off + stAddr[it][1]] = (_Float16)rsStage[it][1];
      }
    }
    if (doMain) {
      f16x8 r0  = ldsFrag(lds, AR + slotA, lane, 0);
      f16x8 r1  = ldsFrag(lds, AR + slotA, lane, 1);
      f16x8 h0  = ldsFrag(lds, AH + ahR, lane, 0);
      f16x8 h1f = ldsFrag(lds, AH + ahR, lane, 1);
      f32x4 cR = {0, 0, 0, 0}, cZ = {0, 0, 0, 0}, cHN = {0, 0, 0, 0}, cIN = {0, 0, 0, 0};
      cR  = MFMA16(h0, fghr[0], cR);  cR  = MFMA16(h1f, fghr[1], cR);
      cZ  = MFMA16(h0, fghz[0], cZ);  cZ  = MFMA16(h1f, fghz[1], cZ);
      cHN = MFMA16(h0, fghn[0], cHN); cHN = MFMA16(h1f, fghn[1], cHN);
      cR  = MFMA16(r0, fgir[0], cR);  cR  = MFMA16(r1, fgir[1], cR);
      cZ  = MFMA16(r0, fgiz[0], cZ);  cZ  = MFMA16(r1, fgiz[1], cZ);
      cIN = MFMA16(r0, fgin[0], cIN); cIN = MFMA16(r1, fgin[1], cIN);
      // redistribute q=2,3 to upper lanes (their own C-rows 8-15 are padding)
      float bR2 = __shfl(cR[2],  l31), bR3 = __shfl(cR[3],  l31);
      float bZ2 = __shfl(cZ[2],  l31), bZ3 = __shfl(cZ[3],  l31);
      float bH2 = __shfl(cHN[2], l31), bH3 = __shfl(cHN[3], l31);
      float bI2 = __shfl(cIN[2], l31), bI3 = __shfl(cIN[3], l31);
      float xRv[2] = { lo ? cR[0]  : bR2, lo ? cR[1]  : bR3 };
      float xZv[2] = { lo ? cZ[0]  : bZ2, lo ? cZ[1]  : bZ3 };
      float xHv[2] = { lo ? cHN[0] : bH2, lo ? cHN[1] : bH3 };
      float xIv[2] = { lo ? cIN[0] : bI2, lo ? cIN[1] : bI3 };
#pragma unroll
      for (int j = 0; j < 2; ++j) {
        float r   = rcpf(1.0f + ex2(fmaf(xRv[j], -C1, nbr2)));
        float z   = rcpf(1.0f + ex2(fmaf(xZv[j], -C1, nbz2)));
        float pre = fmaf(r, xHv[j] + bhn2, xIv[j] + bin2);
        float e2  = ex2(pre * (2.0f * C1));
        float n   = 1.0f - 2.0f * rcpf(1.0f + e2);
        float hv  = fmaf(z, hq2[j] - n, n);
        hq2[j] = hv;
        outp[j * 64] = hv;
        lds[ahW + ahw2[j]] = (_Float16)hv;
      }
      outp += (size_t)B_BATCH * 64;
    }
  };

  // ---- p-wave phase f: p-GRUs(t=f) + gate(t=f-1) ----
  auto pPhase = [&](int pj, int agWr, int aphWr, int gSlot, bool doComp, bool doGate) {
    if (doComp) {
      f16x8 a0 = ldsFrag(lds, apB + pj, lane, 0);
      f16x8 a1 = ldsFrag(lds, apB + pj, lane, 1);
      f16x8 ah = ldsFrag(lds, aphB + pj, lane, 0);
      f32x4 aR = {0, 0, 0, 0}, aZ = {0, 0, 0, 0}, aIN = {0, 0, 0, 0}, aHN = {0, 0, 0, 0};
      aR  = MFMA16(a0, pgi0[0], aR);  aR  = MFMA16(a1, pgi0[1], aR);  aR = MFMA16(ah, pgh0, aR);
      aZ  = MFMA16(a0, pgi1[0], aZ);  aZ  = MFMA16(a1, pgi1[1], aZ);  aZ = MFMA16(ah, pgh1, aZ);
      aIN = MFMA16(a0, pgi2[0], aIN); aIN = MFMA16(a1, pgi2[1], aIN);
      aHN = MFMA16(ah, pgh2, aHN);
      float bR2 = __shfl(aR[2],  l31), bR3 = __shfl(aR[3],  l31);
      float bZ2 = __shfl(aZ[2],  l31), bZ3 = __shfl(aZ[3],  l31);
      float bI2 = __shfl(aIN[2], l31), bI3 = __shfl(aIN[3], l31);
      float bH2 = __shfl(aHN[2], l31), bH3 = __shfl(aHN[3], l31);
      float xRv[2] = { lo ? aR[0]  : bR2, lo ? aR[1]  : bR3 };
      float xZv[2] = { lo ? aZ[0]  : bZ2, lo ? aZ[1]  : bZ3 };
      float xIv[2] = { lo ? aIN[0] : bI2, lo ? aIN[1] : bI3 };
      float xHv[2] = { lo ? aHN[0] : bH2, lo ? aHN[1] : bH3 };
#pragma unroll
      for (int j = 0; j < 2; ++j) {
        float r   = rcpf(1.0f + ex2(fmaf(xRv[j], -C1, nbr)));
        float z   = rcpf(1.0f + ex2(fmaf(xZv[j], -C1, nbz)));
        float pre = fmaf(r, xHv[j] + bhn, xIv[j] + bin);
        float e2  = ex2(pre * (2.0f * C1));
        float n   = 1.0f - 2.0f * rcpf(1.0f + e2);
        float hv  = fmaf(z, h1q2[j] - n, n);
        h1q2[j] = hv;
        if (uok) {
          _Float16 hh = (_Float16)hv;
          lds[agWr + agw2[j]]  = hh;   // -> AG slot f&3 (gate input, read @f+1)
          lds[aphWr + aphw2[j]] = hh;  // -> own h-path, read @f+1
        }
      }
    }
    if (doGate) {
      f16x8 g0 = ldsFrag(lds, AG + gSlot, lane, 0);
      f16x8 g1 = ldsFrag(lds, AG + gSlot, lane, 1);
      f32x4 cG = {0, 0, 0, 0};
      cG = MFMA16(g0, fgw[0], cG); cG = MFMA16(g1, fgw[1], cG);
      float bG2 = __shfl(cG[2], l31), bG3 = __shfl(cG[3], l31);
      float gv0 = lo ? cG[0] : bG2, gv1 = lo ? cG[1] : bG3;
      lds[gSlot + arw2[0]] = (_Float16)fmaxf(gv0 + gbias, 0.0f);  // AR slot (f-1)&3
      lds[gSlot + arw2[1]] = (_Float16)fmaxf(gv1 + gbias, 0.0f);
    }
  };

  // ---- main loop: f = 4i+j, i in [0,127], j in [0,3] ----
  for (int i = 0; i < T_STEPS / 4; ++i) {
    const bool i0 = (i == 0);
    const int f0 = 4 * i;
    // j=0: offP=PX offGR=PX slotA=2PX ahR=PX ahW=0 | p: pj=0 agWr=0 aphWr=PX gSlot=3PX
    if (isR) rPhase(PX, PX, 2 * PX, PX, 0, !i0, true, rs1, rs0, (f0 + 5 < T_STEPS));
    else     pPhase(0, 0, PX, 3 * PX, true, !i0);
    BARRIER();
    // j=1: offP=0 offGR=2PX slotA=3PX ahR=0 ahW=PX | p: pj=PX agWr=PX aphWr=0 gSlot=0
    if (isR) rPhase(0, 2 * PX, 3 * PX, 0, PX, !i0, true, rs2, rs1, (f0 + 6 < T_STEPS));
    else     pPhase(PX, PX, 0, 0, true, true);
    BARRIER();
    // j=2: offP=PX offGR=3PX slotA=0 ahR=PX ahW=0 | p: pj=0 agWr=2PX aphWr=PX gSlot=PX
    if (isR) rPhase(PX, 3 * PX, 0, PX, 0, true, true, rs3, rs2, (f0 + 7 < T_STEPS));
    else     pPhase(0, 2 * PX, PX, PX, true, true);
    BARRIER();
    // j=3: offP=0 offGR=0 slotA=PX ahR=0 ahW=PX | p: pj=PX agWr=3PX aphWr=0 gSlot=2PX
    if (isR) rPhase(0, 0, PX, 0, PX, true, (i != T_STEPS / 4 - 1), rs0, rs3,
                    (f0 + 8 < T_STEPS));
    else     pPhase(PX, 3 * PX, 0, 2 * PX, true, true);
    BARRIER();
  }
  // ---- epilogue: f=512 (even): main(510) slotA=2PX ahR=PX ahW=0; p: gate(511) ----
  if (isR) rPhase(0, 0, 2 * PX, PX, 0, true, false, rs0, rs1, false);
  else     pPhase(0, 0, PX, 3 * PX, false, true);
  BARRIER();
  // ---- f=513 (odd): main(511) slotA=3PX ahR=0 ahW=PX ----
  if (isR) rPhase(0, 0, 3 * PX, 0, PX, true, false, rs0, rs1, false);
}

extern "C" void kernel_launch(void* const* d_in, const int* in_sizes, int n_in,
                              void* d_out, int out_size, void* d_ws, size_t ws_size,
                              hipStream_t stream) {
  (void)in_sizes; (void)n_in; (void)d_ws; (void)ws_size; (void)out_size;
  const float* seq   = (const float*)d_in[0];
  const float* p1Wih = (const float*)d_in[1];
  const float* p1Whh = (const float*)d_in[2];
  const float* p1bih = (const float*)d_in[3];
  const float* p1bhh = (const float*)d_in[4];
  const float* p2Wih = (const float*)d_in[5];
  const float* p2Whh = (const float*)d_in[6];
  const float* p2bih = (const float*)d_in[7];
  const float* p2bhh = (const float*)d_in[8];
  const float* gW    = (const float*)d_in[9];
  const float* gb    = (const float*)d_in[10];
  const float* rWih  = (const float*)d_in[11];
  const float* rWhh  = (const float*)d_in[12];
  const float* rbih  = (const float*)d_in[13];
  const float* rbhh  = (const float*)d_in[14];
  float* out = (float*)d_out;
  hipLaunchKernelGGL(rnn_fused, dim3(NBLOCKS), dim3(512), 0, stream,
                     seq, p1Wih, p1Whh, p1bih, p1bhh,
                     p2Wih, p2Whh, p2bih, p2bhh,
                     gW, gb, rWih, rWhh, rbih, rbhh, out);
}

// Round 12
// 304.718 us; speedup vs baseline: 1.5692x; 1.1515x over previous
//
#include <hip/hip_runtime.h>

// Fused persistent stacked-GRU kernel for MI355X (gfx950).
// Round-12: R11 3-stage pipeline (p||gate||main, gate on p-waves, 1 lean
// barrier/phase) with MIRRORED A-ROW READS: ldsFrag reads row lane&7 (rows
// 8-15 of every A-operand become copies of 0-7), so each upper lane's own
// q=2,3 accumulator elements equal the values R11 moved cross-lane -> all
// ds_bpermute shuffles deleted (addressing-only change, same-address LDS
// reads broadcast for free). Plus persistent zero C-in (no per-phase
// accumulator zero-init). Arithmetic bit-identical to R10/R11.
// 256 blocks x 8 rows, launch_bounds(512,2).

#define T_STEPS 512
#define B_BATCH 2048
#define D_IN    132
#define NROWS   8
#define NBLOCKS 256
#define STEP2   (B_BATCH * D_IN / 2)   // f32x2 per timestep
#define NITEMS  (NROWS * 66)           // 528 f32x2 per step per block

typedef _Float16 f16x8 __attribute__((ext_vector_type(8)));
typedef float    f32x4 __attribute__((ext_vector_type(4)));
typedef float    f32x2 __attribute__((ext_vector_type(2)));

#define MFMA16(a, b, c) __builtin_amdgcn_mfma_f32_16x16x32_f16((a), (b), (c), 0, 0, 0)

// LDS tiles [16 rows][64 cols] fp16 = 1024 elems each; PX = slot stride.
#define PX    1024
#define AP1   0      // x_p1 cols 0..48                  (2 slots)
#define AP2   2048   // x_p2 cols 0..48                  (2 slots)
#define AG    4096   // h1:0-19 h2:20-39 xg:40-47        (4 slots)
#define AR    8192   // gate:0-15 xr:16-41               (4 slots)
#define AP1H  12288  // h1 cols 0..19                    (2 slots)
#define AP2H  14336  // h2 cols 0..19                    (2 slots)
#define AH    16384  // h cols 0..63                     (2 slots)
#define LDS_N 18432

// Raw barrier: LDS visibility only (lgkmcnt), NO vmcnt drain -> HBM prefetch
// stays in flight across barriers. seq read-only, out write-only.
#define BARRIER() do { \
    asm volatile("s_waitcnt lgkmcnt(0)\n\ts_barrier" ::: "memory"); \
    __builtin_amdgcn_sched_barrier(0); \
  } while (0)

__device__ __forceinline__ int swz(int row, int col) {
  return row * 64 + (((col >> 3) ^ (row & 7)) << 3) + (col & 7);
}

// A-fragment read with MIRRORED rows: row = lane&7 (rows 8-15 duplicate 0-7).
__device__ __forceinline__ f16x8 ldsFrag(const _Float16* lds, int base, int lane, int kt) {
  int row = lane & 7;
  int blk = ((kt << 2) + (lane >> 4)) ^ row;
  return *reinterpret_cast<const f16x8*>(lds + base + row * 64 + blk * 8);
}

__device__ __forceinline__ f16x8 mkfrag(const float* W, int row, int K, int kbase, int lane, bool ok) {
  f16x8 f;
  int k0 = kbase + ((lane >> 4) << 3);
#pragma unroll
  for (int j = 0; j < 8; ++j) {
    int k = k0 + j;
    float v = 0.0f;
    if (ok && k < K) v = W[row * K + k];
    f[j] = (_Float16)v;
  }
  return f;
}

__device__ __forceinline__ float rcpf(float x) { return __builtin_amdgcn_rcpf(x); }
__device__ __forceinline__ float ex2(float x)  { return __builtin_amdgcn_exp2f(x); }

__global__ __launch_bounds__(512, 2) void rnn_fused(
    const float* __restrict__ seq,
    const float* __restrict__ p1Wih, const float* __restrict__ p1Whh,
    const float* __restrict__ p1bih, const float* __restrict__ p1bhh,
    const float* __restrict__ p2Wih, const float* __restrict__ p2Whh,
    const float* __restrict__ p2bih, const float* __restrict__ p2bhh,
    const float* __restrict__ gW,    const float* __restrict__ gb,
    const float* __restrict__ rWih,  const float* __restrict__ rWhh,
    const float* __restrict__ rbih,  const float* __restrict__ rbhh,
    float* __restrict__ out)
{
  __shared__ __align__(16) _Float16 lds[LDS_N];
  const int tid  = threadIdx.x;
  const int lane = tid & 63;
  const int wv   = tid >> 6;
  const bool isR = (wv < 4);
  const int b0   = blockIdx.x * NROWS;
  const int ul   = lane & 15;
  const bool lo  = (lane < 32);
  // lanes<32 own rows grp4+{0,1} (their q=0,1); lanes>=32 rows grp4+{2,3}
  // (their own q=2,3, valid because A-rows are mirrored).
  const int grp4 = ((lane >> 4) & 1) * 4;
  const int row0 = grp4 + (lo ? 0 : 2);
  const float C1 = 1.44269504089f;

  for (int i = tid; i < LDS_N; i += 512) lds[i] = (_Float16)0.0f;

  // ---------------- r-wave state (staging + main GRU) ----------------
  f16x8 fghr[2], fghz[2], fghn[2], fgir[2], fgiz[2], fgin[2];
  float nbr2 = 0, nbz2 = 0, bin2 = 0, bhn2 = 0;
  float hq2[2] = {0, 0};
  int stAddr[3][2]; int ldIdx[3] = {0, 0, 0};
  bool stOK[3] = {false, false, false}, isP[3] = {false, false, false};
  int ahw2[2] = {0, 0};
  float* outp = nullptr;

  // ---------------- p-wave state (p-GRUs + gate) ----------------
  f16x8 pgi0[2], pgi1[2], pgi2[2], pgh0, pgh1, pgh2, fgw[2];
  float nbr = 0, nbz = 0, bin = 0, bhn = 0, gbias = 0;
  float h1q2[2] = {0, 0};
  int apB = 0, aphB = 0, up = 0; bool uok = false;
  int agw2[2] = {0, 0}, aphw2[2] = {0, 0}, arw2[2] = {0, 0};

  if (isR) {
    const int uR = wv * 16 + ul;
    fghr[0] = mkfrag(rWhh,       uR, 64,  0, lane, true);
    fghr[1] = mkfrag(rWhh,       uR, 64, 32, lane, true);
    fghz[0] = mkfrag(rWhh,  64 + uR, 64,  0, lane, true);
    fghz[1] = mkfrag(rWhh,  64 + uR, 64, 32, lane, true);
    fghn[0] = mkfrag(rWhh, 128 + uR, 64,  0, lane, true);
    fghn[1] = mkfrag(rWhh, 128 + uR, 64, 32, lane, true);
    fgir[0] = mkfrag(rWih,       uR, 42,  0, lane, true);
    fgir[1] = mkfrag(rWih,       uR, 42, 32, lane, true);
    fgiz[0] = mkfrag(rWih,  64 + uR, 42,  0, lane, true);
    fgiz[1] = mkfrag(rWih,  64 + uR, 42, 32, lane, true);
    fgin[0] = mkfrag(rWih, 128 + uR, 42,  0, lane, true);
    fgin[1] = mkfrag(rWih, 128 + uR, 42, 32, lane, true);
    nbr2 = -C1 * (rbih[uR] + rbhh[uR]);
    nbz2 = -C1 * (rbih[64 + uR] + rbhh[64 + uR]);
    bin2 = rbih[128 + uR]; bhn2 = rbhh[128 + uR];
    ahw2[0] = AH + swz(row0, uR);
    ahw2[1] = AH + swz(row0 + 1, uR);
    // staging map: 528 f32x2 items over 256 r-threads, 3 item-slots
#pragma unroll
    for (int it = 0; it < 3; ++it) {
      int ii = it * 256 + (wv * 64 + lane);
      stOK[it] = (ii < NITEMS);
      int iic = stOK[it] ? ii : (NITEMS - 1);
      ldIdx[it] = iic;
      int rr = iic / 66, c2 = iic % 66;
      isP[it] = (c2 < 49);
#pragma unroll
      for (int e = 0; e < 2; ++e) {
        int c = c2 * 2 + e;
        int tb, col;
        if (c < 49)       { tb = AP1; col = c; }
        else if (c < 98)  { tb = AP2; col = c - 49; }
        else if (c < 106) { tb = AG;  col = 40 + (c - 98); }
        else              { tb = AR;  col = 16 + (c - 106); }
        stAddr[it][e] = tb + swz(rr, col);
      }
    }
    outp = out + (size_t)(b0 + row0) * 64 + uR;
  } else {
    const int pw  = wv - 4;
    const int gru = pw >> 1;
    const int s   = pw & 1;
    const float* Wih = gru ? p2Wih : p1Wih;
    const float* Whh = gru ? p2Whh : p1Whh;
    const float* bih = gru ? p2bih : p1bih;
    const float* bhh = gru ? p2bhh : p1bhh;
    up  = s * 16 + ul;
    uok = (up < 20);
    pgi0[0] = mkfrag(Wih,      up, 49,  0, lane, uok);
    pgi0[1] = mkfrag(Wih,      up, 49, 32, lane, uok);
    pgh0    = mkfrag(Whh,      up, 20,  0, lane, uok);
    pgi1[0] = mkfrag(Wih, 20 + up, 49,  0, lane, uok);
    pgi1[1] = mkfrag(Wih, 20 + up, 49, 32, lane, uok);
    pgh1    = mkfrag(Whh, 20 + up, 20,  0, lane, uok);
    pgi2[0] = mkfrag(Wih, 40 + up, 49,  0, lane, uok);
    pgi2[1] = mkfrag(Wih, 40 + up, 49, 32, lane, uok);
    pgh2    = mkfrag(Whh, 40 + up, 20,  0, lane, uok);
    fgw[0]  = mkfrag(gW, ul, 48,  0, lane, true);
    fgw[1]  = mkfrag(gW, ul, 48, 32, lane, true);
    gbias = gb[ul];
    if (uok) {
      nbr = -C1 * (bih[up] + bhh[up]);
      nbz = -C1 * (bih[20 + up] + bhh[20 + up]);
      bin = bih[40 + up]; bhn = bhh[40 + up];
    }
    apB  = gru ? AP2  : AP1;
    aphB = gru ? AP2H : AP1H;
    const int gcol = gru ? (20 + up) : up;
#pragma unroll
    for (int j = 0; j < 2; ++j) {
      agw2[j]  = AG + swz(row0 + j, gcol);
      aphw2[j] = aphB + swz(row0 + j, up);
      arw2[j]  = AR + swz(row0 + j, ul);
    }
  }

  __syncthreads();  // zeros visible

  // ---- prologue (r-waves): load x(0..3) into 4 slots; stage x(0) -> slot 0 ----
  f32x2 rs0[3], rs1[3], rs2[3], rs3[3];
  const f32x2* spR = nullptr;
  if (isR) {
    const f32x2* sp = reinterpret_cast<const f32x2*>(seq) + (size_t)b0 * (D_IN / 2);
#pragma unroll
    for (int it = 0; it < 3; ++it) {
      rs0[it] = sp[ldIdx[it]];
      rs1[it] = sp[(size_t)1 * STEP2 + ldIdx[it]];
      rs2[it] = sp[(size_t)2 * STEP2 + ldIdx[it]];
      rs3[it] = sp[(size_t)3 * STEP2 + ldIdx[it]];
    }
#pragma unroll
    for (int it = 0; it < 3; ++it) if (stOK[it]) {
      lds[stAddr[it][0]] = (_Float16)rs0[it][0];   // all classes -> slot 0
      lds[stAddr[it][1]] = (_Float16)rs0[it][1];
    }
    spR = sp + (size_t)4 * STEP2;
  }
  __syncthreads();

  const f32x4 Z = {0.0f, 0.0f, 0.0f, 0.0f};  // persistent zero C-in

  // ---- r-wave phase f: stage x(f+1), prefetch x(f+4), main(t=f-2) ----
  auto rPhase = [&](int offP, int offGR, int slotA, int ahR, int ahW,
                    bool doMain, bool doStage, f32x2 (&rsStage)[3], f32x2 (&rsLoad)[3],
                    bool advance) {
    // prefetch x(min(f+4,511)); stays in flight past barriers
#pragma unroll
    for (int it = 0; it < 3; ++it) rsLoad[it] = spR[ldIdx[it]];
    if (advance) spR += STEP2;
    if (doStage) {
#pragma unroll
      for (int it = 0; it < 3; ++it) if (stOK[it]) {
        const int off = isP[it] ? offP : offGR;
        lds[off + stAddr[it][0]] = (_Float16)rsStage[it][0];
        lds[off + stAddr[it][1]] = (_Float16)rsStage[it][1];
      }
    }
    if (doMain) {
      f16x8 r0  = ldsFrag(lds, AR + slotA, lane, 0);
      f16x8 r1  = ldsFrag(lds, AR + slotA, lane, 1);
      f16x8 h0  = ldsFrag(lds, AH + ahR, lane, 0);
      f16x8 h1f = ldsFrag(lds, AH + ahR, lane, 1);
      f32x4 cR  = MFMA16(h0, fghr[0], Z);
      f32x4 cZ  = MFMA16(h0, fghz[0], Z);
      f32x4 cHN = MFMA16(h0, fghn[0], Z);
      cR  = MFMA16(h1f, fghr[1], cR);
      cZ  = MFMA16(h1f, fghz[1], cZ);
      cHN = MFMA16(h1f, fghn[1], cHN);
      cR  = MFMA16(r0, fgir[0], cR);  cR  = MFMA16(r1, fgir[1], cR);
      cZ  = MFMA16(r0, fgiz[0], cZ);  cZ  = MFMA16(r1, fgiz[1], cZ);
      f32x4 cIN = MFMA16(r0, fgin[0], Z);
      cIN = MFMA16(r1, fgin[1], cIN);
      // upper lanes use their OWN q=2,3 (valid: mirrored A-rows)
      float xRv[2] = { lo ? cR[0]  : cR[2],  lo ? cR[1]  : cR[3]  };
      float xZv[2] = { lo ? cZ[0]  : cZ[2],  lo ? cZ[1]  : cZ[3]  };
      float xHv[2] = { lo ? cHN[0] : cHN[2], lo ? cHN[1] : cHN[3] };
      float xIv[2] = { lo ? cIN[0] : cIN[2], lo ? cIN[1] : cIN[3] };
#pragma unroll
      for (int j = 0; j < 2; ++j) {
        float r   = rcpf(1.0f + ex2(fmaf(xRv[j], -C1, nbr2)));
        float z   = rcpf(1.0f + ex2(fmaf(xZv[j], -C1, nbz2)));
        float pre = fmaf(r, xHv[j] + bhn2, xIv[j] + bin2);
        float e2  = ex2(pre * (2.0f * C1));
        float n   = 1.0f - 2.0f * rcpf(1.0f + e2);
        float hv  = fmaf(z, hq2[j] - n, n);
        hq2[j] = hv;
        outp[j * 64] = hv;
        lds[ahW + ahw2[j]] = (_Float16)hv;
      }
      outp += (size_t)B_BATCH * 64;
    }
  };

  // ---- p-wave phase f: p-GRUs(t=f) + gate(t=f-1) ----
  auto pPhase = [&](int pj, int agWr, int aphWr, int gSlot, bool doComp, bool doGate) {
    if (doComp) {
      f16x8 a0 = ldsFrag(lds, apB + pj, lane, 0);
      f16x8 a1 = ldsFrag(lds, apB + pj, lane, 1);
      f16x8 ah = ldsFrag(lds, aphB + pj, lane, 0);
      f32x4 aR  = MFMA16(a0, pgi0[0], Z);
      f32x4 aZ  = MFMA16(a0, pgi1[0], Z);
      f32x4 aIN = MFMA16(a0, pgi2[0], Z);
      f32x4 aHN = MFMA16(ah, pgh2, Z);
      aR  = MFMA16(a1, pgi0[1], aR);  aR = MFMA16(ah, pgh0, aR);
      aZ  = MFMA16(a1, pgi1[1], aZ);  aZ = MFMA16(ah, pgh1, aZ);
      aIN = MFMA16(a1, pgi2[1], aIN);
      float xRv[2] = { lo ? aR[0]  : aR[2],  lo ? aR[1]  : aR[3]  };
      float xZv[2] = { lo ? aZ[0]  : aZ[2],  lo ? aZ[1]  : aZ[3]  };
      float xIv[2] = { lo ? aIN[0] : aIN[2], lo ? aIN[1] : aIN[3] };
      float xHv[2] = { lo ? aHN[0] : aHN[2], lo ? aHN[1] : aHN[3] };
#pragma unroll
      for (int j = 0; j < 2; ++j) {
        float r   = rcpf(1.0f + ex2(fmaf(xRv[j], -C1, nbr)));
        float z   = rcpf(1.0f + ex2(fmaf(xZv[j], -C1, nbz)));
        float pre = fmaf(r, xHv[j] + bhn, xIv[j] + bin);
        float e2  = ex2(pre * (2.0f * C1));
        float n   = 1.0f - 2.0f * rcpf(1.0f + e2);
        float hv  = fmaf(z, h1q2[j] - n, n);
        h1q2[j] = hv;
        if (uok) {
          _Float16 hh = (_Float16)hv;
          lds[agWr + agw2[j]]  = hh;   // -> AG slot f&3 (gate input, read @f+1)
          lds[aphWr + aphw2[j]] = hh;  // -> own h-path, read @f+1
        }
      }
    }
    if (doGate) {
      f16x8 g0 = ldsFrag(lds, AG + gSlot, lane, 0);
      f16x8 g1 = ldsFrag(lds, AG + gSlot, lane, 1);
      f32x4 cG = MFMA16(g0, fgw[0], Z);
      cG = MFMA16(g1, fgw[1], cG);
      float gv0 = lo ? cG[0] : cG[2], gv1 = lo ? cG[1] : cG[3];
      lds[gSlot + arw2[0]] = (_Float16)fmaxf(gv0 + gbias, 0.0f);  // AR slot (f-1)&3
      lds[gSlot + arw2[1]] = (_Float16)fmaxf(gv1 + gbias, 0.0f);
    }
  };

  // ---- main loop: f = 4i+j, i in [0,127], j in [0,3] ----
  for (int i = 0; i < T_STEPS / 4; ++i) {
    const bool i0 = (i == 0);
    const int f0 = 4 * i;
    // j=0: offP=PX offGR=PX slotA=2PX ahR=PX ahW=0 | p: pj=0 agWr=0 aphWr=PX gSlot=3PX
    if (isR) rPhase(PX, PX, 2 * PX, PX, 0, !i0, true, rs1, rs0, (f0 + 5 < T_STEPS));
    else     pPhase(0, 0, PX, 3 * PX, true, !i0);
    BARRIER();
    // j=1: offP=0 offGR=2PX slotA=3PX ahR=0 ahW=PX | p: pj=PX agWr=PX aphWr=0 gSlot=0
    if (isR) rPhase(0, 2 * PX, 3 * PX, 0, PX, !i0, true, rs2, rs1, (f0 + 6 < T_STEPS));
    else     pPhase(PX, PX, 0, 0, true, true);
    BARRIER();
    // j=2: offP=PX offGR=3PX slotA=0 ahR=PX ahW=0 | p: pj=0 agWr=2PX aphWr=PX gSlot=PX
    if (isR) rPhase(PX, 3 * PX, 0, PX, 0, true, true, rs3, rs2, (f0 + 7 < T_STEPS));
    else     pPhase(0, 2 * PX, PX, PX, true, true);
    BARRIER();
    // j=3: offP=0 offGR=0 slotA=PX ahR=0 ahW=PX | p: pj=PX agWr=3PX aphWr=0 gSlot=2PX
    if (isR) rPhase(0, 0, PX, 0, PX, true, (i != T_STEPS / 4 - 1), rs0, rs3,
                    (f0 + 8 < T_STEPS));
    else     pPhase(PX, 3 * PX, 0, 2 * PX, true, true);
    BARRIER();
  }
  // ---- epilogue: f=512 (even): main(510) slotA=2PX ahR=PX ahW=0; p: gate(511) ----
  if (isR) rPhase(0, 0, 2 * PX, PX, 0, true, false, rs0, rs1, false);
  else     pPhase(0, 0, PX, 3 * PX, false, true);
  BARRIER();
  // ---- f=513 (odd): main(511) slotA=3PX ahR=0 ahW=PX ----
  if (isR) rPhase(0, 0, 3 * PX, 0, PX, true, false, rs0, rs1, false);
}

extern "C" void kernel_launch(void* const* d_in, const int* in_sizes, int n_in,
                              void* d_out, int out_size, void* d_ws, size_t ws_size,
                              hipStream_t stream) {
  (void)in_sizes; (void)n_in; (void)d_ws; (void)ws_size; (void)out_size;
  const float* seq   = (const float*)d_in[0];
  const float* p1Wih = (const float*)d_in[1];
  const float* p1Whh = (const float*)d_in[2];
  const float* p1bih = (const float*)d_in[3];
  const float* p1bhh = (const float*)d_in[4];
  const float* p2Wih = (const float*)d_in[5];
  const float* p2Whh = (const float*)d_in[6];
  const float* p2bih = (const float*)d_in[7];
  const float* p2bhh = (const float*)d_in[8];
  const float* gW    = (const float*)d_in[9];
  const float* gb    = (const float*)d_in[10];
  const float* rWih  = (const float*)d_in[11];
  const float* rWhh  = (const float*)d_in[12];
  const float* rbih  = (const float*)d_in[13];
  const float* rbhh  = (const float*)d_in[14];
  float* out = (float*)d_out;
  hipLaunchKernelGGL(rnn_fused, dim3(NBLOCKS), dim3(512), 0, stream,
                     seq, p1Wih, p1Whh, p1bih, p1bhh,
                     p2Wih, p2Whh, p2bih, p2bhh,
                     gW, gb, rWih, rWhh, rbih, rbhh, out);
}